// Round 3
// baseline (247.813 us; speedup 1.0000x reference)
//
#include <hip/hip_runtime.h>
#include <hip/hip_bf16.h>

#define GDIM 38
#define GG   (GDIM * GDIM)          // 1444
#define TOTAL (GDIM * GDIM * GDIM)  // 54872

// 13 half-shell displacements (buckets_per_cutoff == 1), matches VEC_DISP
__device__ __constant__ int c_disp[13][3] = {
    {-1, 0, 0}, {-1, -1, 0}, {0, -1, 0}, {1, -1, 0},
    {-1, 1, -1}, {0, 1, -1}, {1, 1, -1}, {-1, 0, -1},
    {0, 0, -1}, {1, 0, -1}, {-1, -1, -1}, {0, -1, -1}, {1, -1, -1}};

// translation-case LUT indexed by cx*9+cy*3+cz, cat: 0=low(0), 1=mid, 2=high(G+1)
__device__ __constant__ unsigned char c_case[27] = {
    11,  2, 0,   8,  1, 0,   5, 14, 0,
    12,  3, 0,   9,  0, 0,   6, 15, 0,
    13,  4, 0,  10, 17, 0,   7, 16, 0};

__global__ __launch_bounds__(256) void cell_atoms_kernel(
    const float* __restrict__ coords, const float* __restrict__ cell,
    float* __restrict__ out, int* __restrict__ cnt, int N)
{
    int i = blockIdx.x * blockDim.x + threadIdx.x;
    if (i >= N) return;

    const long long OFF0 = 0;            // frac       (3N)
    const long long OFF1 = 3LL * N;      // flat index (N)
    const long long OFF2 = 4LL * N;      // neigh flat (13N)
    const long long OFF3 = 17LL * N;     // neigh case (13N)

    int v[3];
#pragma unroll
    for (int a = 0; a < 3; ++a) {
        float d = cell[4 * a];                 // diagonal: cell[0],cell[4],cell[8]
        float f = coords[3 * i + a] / d;       // IEEE divide, matches jnp
        f = f - floorf(f);
        if (f >= 1.0f) f -= 1.0f;
        if (f < 0.0f)  f += 1.0f;
        out[OFF0 + 3LL * i + a] = f;
        v[a] = (int)floorf(f * (float)GDIM);
    }

    int flat = v[0] * GG + v[1] * GDIM + v[2];
    out[OFF1 + i] = (float)flat;
    atomicAdd(&cnt[flat], 1);

#pragma unroll
    for (int k = 0; k < 13; ++k) {
        int cidx = 0, nf = 0;
#pragma unroll
        for (int a = 0; a < 3; ++a) {
            int n = v[a] + 1 + c_disp[k][a];   // padded-grid coordinate, [0, G+1]
            int cat = (n == 0) ? 0 : ((n == GDIM + 1) ? 2 : 1);
            int m = (n == 0) ? (GDIM - 1) : ((n == GDIM + 1) ? 0 : n - 1);
            cidx = cidx * 3 + cat;
            nf += m * (a == 0 ? GG : (a == 1 ? GDIM : 1));
        }
        out[OFF2 + 13LL * i + k] = (float)nf;
        out[OFF3 + 13LL * i + k] = (float)c_case[cidx];
    }
}

__global__ __launch_bounds__(1024) void scan_kernel(
    const int* __restrict__ cnt,
    float* __restrict__ out_count,
    float* __restrict__ out_cum)
{
    const int C = (TOTAL + 1023) / 1024;   // 54 elements per thread
    __shared__ int ssum[1024];
    int t = threadIdx.x;
    int base = t * C;

    int s = 0;
    for (int j = 0; j < C; ++j) {
        int idx = base + j;
        if (idx < TOTAL) s += cnt[idx];
    }
    ssum[t] = s;
    __syncthreads();

    // Hillis–Steele inclusive scan over 1024 per-thread sums
    for (int off = 1; off < 1024; off <<= 1) {
        int vprev = (t >= off) ? ssum[t - off] : 0;
        __syncthreads();
        ssum[t] += vprev;
        __syncthreads();
    }

    int run = (t == 0) ? 0 : ssum[t - 1];  // exclusive prefix of this chunk
    for (int j = 0; j < C; ++j) {
        int idx = base + j;
        if (idx < TOTAL) {
            int c = cnt[idx];
            out_cum[idx]   = (float)run;
            out_count[idx] = (float)c;
            run += c;
        }
    }
}

extern "C" void kernel_launch(void* const* d_in, const int* in_sizes, int n_in,
                              void* d_out, int out_size, void* d_ws, size_t ws_size,
                              hipStream_t stream)
{
    const float* coords = (const float*)d_in[0];
    const float* cell   = (const float*)d_in[1];
    float* out = (float*)d_out;
    int* cnt = (int*)d_ws;

    // Derive N unambiguously from out_size: out_size = 30N + 2*TOTAL
    int N = (int)((out_size - 2 * TOTAL) / 30);

    // zero the histogram workspace every call (harness does not re-poison)
    hipMemsetAsync(cnt, 0, TOTAL * sizeof(int), stream);

    cell_atoms_kernel<<<(N + 255) / 256, 256, 0, stream>>>(coords, cell, out, cnt, N);

    long long off4 = 30LL * N;  // count then cumcount at the tail
    scan_kernel<<<1, 1024, 0, stream>>>(cnt, out + off4, out + off4 + TOTAL);
}

// Round 4
// 69.836 us; speedup vs baseline: 3.5485x; 3.5485x over previous
//
#include <hip/hip_runtime.h>

#define GDIM 38
#define GG   (GDIM * GDIM)          // 1444
#define TOTAL (GDIM * GDIM * GDIM)  // 54872

// 13 half-shell displacements (buckets_per_cutoff == 1), matches VEC_DISP
__device__ __constant__ int c_disp[13][3] = {
    {-1, 0, 0}, {-1, -1, 0}, {0, -1, 0}, {1, -1, 0},
    {-1, 1, -1}, {0, 1, -1}, {1, 1, -1}, {-1, 0, -1},
    {0, 0, -1}, {1, 0, -1}, {-1, -1, -1}, {0, -1, -1}, {1, -1, -1}};

// translation-case LUT indexed by cx*9+cy*3+cz, cat: 0=low(0), 1=mid, 2=high(G+1)
__device__ __constant__ unsigned char c_case[27] = {
    11,  2, 0,   8,  1, 0,   5, 14, 0,
    12,  3, 0,   9,  0, 0,   6, 15, 0,
    13,  4, 0,  10, 17, 0,   7, 16, 0};

#define BS 256

__global__ __launch_bounds__(BS) void cell_atoms_kernel(
    const float* __restrict__ coords, const float* __restrict__ cell,
    float* __restrict__ out, int* __restrict__ cnt, int N)
{
    __shared__ float s[13 * BS];   // staging buffer, reused across phases

    const int tid = threadIdx.x;
    const long long blockbase = (long long)blockIdx.x * BS;
    const int valid = (int)min((long long)BS, (long long)N - blockbase);
    const int i_ok = tid < valid;

    const long long OFF0 = 0;            // frac       (3N)
    const long long OFF1 = 3LL * N;      // flat index (N)
    const long long OFF2 = 4LL * N;      // neigh flat (13N)
    const long long OFF3 = 17LL * N;     // neigh case (13N)

    // ---- phase 0: coalesced load of this block's coords into LDS ----
    {
        const float* src = coords + blockbase * 3;
        int lim = valid * 3;
        for (int j = tid; j < lim; j += BS) s[j] = src[j];
    }
    __syncthreads();

    // ---- per-atom compute (from LDS; stride-3 read is 2-way aliasing = free)
    int v[3];
    float fr[3];
    if (i_ok) {
#pragma unroll
        for (int a = 0; a < 3; ++a) {
            float d = cell[4 * a];              // diagonal
            float f = s[3 * tid + a] / d;       // IEEE divide, matches jnp
            f = f - floorf(f);
            if (f >= 1.0f) f -= 1.0f;
            if (f < 0.0f)  f += 1.0f;
            fr[a] = f;
            v[a] = (int)floorf(f * (float)GDIM);
        }
    }
    __syncthreads();

    // ---- phase 1: frac → LDS → coalesced store ----
    if (i_ok) {
#pragma unroll
        for (int a = 0; a < 3; ++a) s[3 * tid + a] = fr[a];
    }
    __syncthreads();
    {
        float* dst = out + OFF0 + blockbase * 3;
        int lim = valid * 3;
        for (int j = tid; j < lim; j += BS) dst[j] = s[j];
    }

    // ---- flat index (already coalesced) + histogram ----
    int flat = 0;
    if (i_ok) {
        flat = v[0] * GG + v[1] * GDIM + v[2];
        out[OFF1 + blockbase + tid] = (float)flat;
        atomicAdd(&cnt[flat], 1);
    }

    // ---- neighbor flat + case ----
    int nf[13], nc[13];
    if (i_ok) {
#pragma unroll
        for (int k = 0; k < 13; ++k) {
            int cidx = 0, f2 = 0;
#pragma unroll
            for (int a = 0; a < 3; ++a) {
                int n = v[a] + 1 + c_disp[k][a];   // padded coord, [0, G+1]
                int cat = (n == 0) ? 0 : ((n == GDIM + 1) ? 2 : 1);
                int m = (n == 0) ? (GDIM - 1) : ((n == GDIM + 1) ? 0 : n - 1);
                cidx = cidx * 3 + cat;
                f2 += m * (a == 0 ? GG : (a == 1 ? GDIM : 1));
            }
            nf[k] = f2;
            nc[k] = c_case[cidx];
        }
    }

    // ---- phase 2: neighbor flat → LDS → coalesced store ----
    __syncthreads();
    if (i_ok) {
#pragma unroll
        for (int k = 0; k < 13; ++k) s[13 * tid + k] = (float)nf[k];
    }
    __syncthreads();
    {
        float* dst = out + OFF2 + blockbase * 13;
        int lim = valid * 13;
        for (int j = tid; j < lim; j += BS) dst[j] = s[j];
    }

    // ---- phase 3: neighbor case → LDS → coalesced store ----
    __syncthreads();
    if (i_ok) {
#pragma unroll
        for (int k = 0; k < 13; ++k) s[13 * tid + k] = (float)nc[k];
    }
    __syncthreads();
    {
        float* dst = out + OFF3 + blockbase * 13;
        int lim = valid * 13;
        for (int j = tid; j < lim; j += BS) dst[j] = s[j];
    }
}

// Parallel scan: 54 blocks; each block sums everything before its range
// (L2-resident, coalesced) and block-scans its own 1024 counts.
__global__ __launch_bounds__(1024) void scan_kernel(
    const int* __restrict__ cnt,
    float* __restrict__ out_count,
    float* __restrict__ out_cum)
{
    __shared__ int lds[1024];
    const int t = threadIdx.x;
    const int base = blockIdx.x * 1024;

    // 1) prefix base = sum of cnt[0..base)  (coalesced, L2-hit)
    int pre = 0;
    for (int j = t; j < base; j += 1024) pre += cnt[j];
    lds[t] = pre;
    __syncthreads();
    for (int off = 512; off > 0; off >>= 1) {
        if (t < off) lds[t] += lds[t + off];
        __syncthreads();
    }
    const int blockpre = lds[0];
    __syncthreads();

    // 2) own element
    const int idx = base + t;
    const int c = (idx < TOTAL) ? cnt[idx] : 0;

    // 3) intra-block inclusive scan (Hillis–Steele)
    lds[t] = c;
    __syncthreads();
    for (int off = 1; off < 1024; off <<= 1) {
        int vprev = (t >= off) ? lds[t - off] : 0;
        __syncthreads();
        lds[t] += vprev;
        __syncthreads();
    }
    const int exc = lds[t] - c;

    if (idx < TOTAL) {
        out_count[idx] = (float)c;
        out_cum[idx]   = (float)(blockpre + exc);
    }
}

extern "C" void kernel_launch(void* const* d_in, const int* in_sizes, int n_in,
                              void* d_out, int out_size, void* d_ws, size_t ws_size,
                              hipStream_t stream)
{
    const float* coords = (const float*)d_in[0];
    const float* cell   = (const float*)d_in[1];
    float* out = (float*)d_out;
    int* cnt = (int*)d_ws;

    // out_size = 30N + 2*TOTAL
    int N = (int)((out_size - 2 * TOTAL) / 30);

    hipMemsetAsync(cnt, 0, TOTAL * sizeof(int), stream);

    cell_atoms_kernel<<<(N + BS - 1) / BS, BS, 0, stream>>>(coords, cell, out, cnt, N);

    long long off4 = 30LL * N;  // count then cumcount at the tail
    scan_kernel<<<(TOTAL + 1023) / 1024, 1024, 0, stream>>>(
        cnt, out + off4, out + off4 + TOTAL);
}